// Round 6
// baseline (161.201 us; speedup 1.0000x reference)
//
#include <hip/hip_runtime.h>
#include <math.h>

#define FEAT 256
#define NB   16
#define TLEN 4096
#define NROWS (NB * TLEN)

// ws layout (element offsets, 4B elements)
#define OFF_BEFF  0                       // float
#define OFF_PART  2                       // float[8][1280] weff partials
#define OFF_ALPHA (OFF_PART + 8 * 1280)   // float[NB][TLEN]
#define OFF_W1    (OFF_ALPHA + NROWS)     // float[NB][TLEN]
#define OFF_W2    (OFF_W1 + NROWS)        // float[NB][TLEN]
#define OFF_FPOS  (OFF_W2 + NROWS)        // int[NB][TLEN]
#define OFF_NF    (OFF_FPOS + NROWS)      // int[NB]

// K1: blocks 0..39 compute w_eff partial sums over 32-wide o-chunks;
// block 40 computes b_eff completely.
__global__ __launch_bounds__(256) void weff1_kernel(
    const float* __restrict__ conv_w, const float* __restrict__ conv_b,
    const float* __restrict__ lin_w, const float* __restrict__ lin_b,
    float* __restrict__ ws) {
  if (blockIdx.x < 40) {
    int ob = blockIdx.x % 5, oc = blockIdx.x / 5;
    int idx = ob * 256 + threadIdx.x;    // idx = i*5 + k (coalesced over o-rows)
    float acc = 0.f;
    int o0 = oc * 32;
#pragma unroll 8
    for (int o = o0; o < o0 + 32; ++o)
      acc = fmaf(conv_w[o * (FEAT * 5) + idx], lin_w[o], acc);
    ws[OFF_PART + oc * 1280 + idx] = acc;
  } else {
    __shared__ float red[256];
    red[threadIdx.x] = conv_b[threadIdx.x] * lin_w[threadIdx.x];
    __syncthreads();
    for (int s = 128; s > 0; s >>= 1) {
      if (threadIdx.x < s) red[threadIdx.x] += red[threadIdx.x + s];
      __syncthreads();
    }
    if (threadIdx.x == 0) ws[OFF_BEFF] = red[0] + lin_b[0];
  }
}

// K2: fused pdot + z + sigmoid.  Block = 128 timesteps of one batch.
// Reduces w_eff partials into LDS, computes row-dots P[5][row] for its
// 132-row halo window (8-lane groups, w4 hoisted fpass-outer), then
// z[t] = b_eff + sum_k P[k][t+k-2] and alpha = sigmoid(z).
__global__ __launch_bounds__(256) void pdalpha_kernel(
    const float* __restrict__ x, float* __restrict__ ws) {
  __shared__ float sW[5 * 256];   // w_eff[k][i]
  __shared__ float sP[5 * 132];   // P[k][local row]
  const int tid = threadIdx.x;

  // reduce the 8 o-chunk partials -> sW
#pragma unroll
  for (int j = 0; j < 5; ++j) {
    int idx = j * 256 + tid;
    float acc = 0.f;
#pragma unroll
    for (int c = 0; c < 8; ++c) acc += ws[OFF_PART + c * 1280 + idx];
    int i = idx / 5, k = idx - i * 5;
    sW[k * 256 + i] = acc;
  }
  const float b_eff = ws[OFF_BEFF];
  __syncthreads();

  const int t0 = blockIdx.x * 128;
  const int bs = (t0 >> 12) << 12;           // batch start row
  const int be = bs + TLEN;                  // batch end row
  const int lo = t0 - 2;                     // local index base
  const int start = lo < bs ? bs : lo;
  const int end0  = t0 + 130;
  const int end   = end0 > be ? be : end0;
  const int cnt   = end - start;             // rows to dot (130 or 132)

  const int wave = tid >> 6, l = tid & 63, l8 = l & 7, g8 = l >> 3;
  float p[5][5];                             // [row-pass][k]
#pragma unroll
  for (int rp = 0; rp < 5; ++rp)
#pragma unroll
    for (int k = 0; k < 5; ++k) p[rp][k] = 0.f;

  int j0 = wave * 8 + g8;                    // this group's row in pass 0
#pragma unroll
  for (int fp = 0; fp < 8; ++fp) {
    float4 w4[5];
#pragma unroll
    for (int k = 0; k < 5; ++k)
      w4[k] = *(const float4*)&sW[k * 256 + fp * 32 + l8 * 4];
#pragma unroll
    for (int rp = 0; rp < 5; ++rp) {
      int j = rp * 32 + j0;
      if (j < cnt) {
        float4 xv = *(const float4*)(x + (size_t)(start + j) * FEAT + fp * 32 + l8 * 4);
#pragma unroll
        for (int k = 0; k < 5; ++k)
          p[rp][k] = fmaf(xv.x, w4[k].x, fmaf(xv.y, w4[k].y,
                      fmaf(xv.z, w4[k].z, fmaf(xv.w, w4[k].w, p[rp][k]))));
      }
    }
  }
#pragma unroll
  for (int rp = 0; rp < 5; ++rp) {
    int j = rp * 32 + j0;
#pragma unroll
    for (int k = 0; k < 5; ++k) {
      p[rp][k] += __shfl_xor(p[rp][k], 1);
      p[rp][k] += __shfl_xor(p[rp][k], 2);
      p[rp][k] += __shfl_xor(p[rp][k], 4);
    }
    if (l8 == 0 && j < cnt) {
      int jl = (start + j) - lo;
#pragma unroll
      for (int k = 0; k < 5; ++k) sP[k * 132 + jl] = p[rp][k];
    }
  }
  __syncthreads();

  if (tid < 128) {
    int t = t0 + tid;
    float z = b_eff;
#pragma unroll
    for (int k = 0; k < 5; ++k) {
      int tt = t + k - 2;
      if (tt >= bs && tt < be) z += sP[k * 132 + (tt - lo)];
    }
    ws[OFF_ALPHA + t] = 1.f / (1.f + expf(-z));
  }
}

// K3: one block per batch, 1024 threads.  Per-element Hillis-Steele f64
// scan of all 4096 alphas in LDS (every St/Sp pair reads the SAME stored
// value -> exact adjacent consistency, fires bijective with fpos).
__global__ __launch_bounds__(1024) void scan_kernel(
    float* __restrict__ ws, float* __restrict__ out) {
  const int b = blockIdx.x;
  const int tid = threadIdx.x;
  __shared__ double sS[TLEN];   // 32 KB
#pragma unroll
  for (int r = 0; r < 4; ++r) {
    int t = r * 1024 + tid;
    sS[t] = (double)ws[OFF_ALPHA + b * TLEN + t];
  }
  __syncthreads();
  for (int s = 1; s < TLEN; s <<= 1) {
    double add[4];
#pragma unroll
    for (int r = 0; r < 4; ++r) {
      int t = r * 1024 + tid;
      add[r] = (t >= s) ? sS[t - s] : 0.0;
    }
    __syncthreads();
#pragma unroll
    for (int r = 0; r < 4; ++r) sS[r * 1024 + tid] += add[r];
    __syncthreads();
  }
#pragma unroll
  for (int r = 0; r < 4; ++r) {
    int t = r * 1024 + tid;
    double St = sS[t];
    double Sp = t ? sS[t - 1] : 0.0;
    double Ft = floor(St), Fp = floor(Sp);
    ws[OFF_W1 + b * TLEN + t] = (float)(fmin(St, Fp + 1.0) - Sp);  // alpha or a1
    if (Ft > Fp) {
      ws[OFF_W2 + b * TLEN + t] = (float)(St - Ft);                // a2
      ((int*)ws)[OFF_FPOS + b * TLEN + (int)Ft - 1] = t;           // fire pos
    }
    if (t == TLEN - 1) {
      int n = (int)Ft;
      ((int*)ws)[OFF_NF + b] = n;
      out[(size_t)NROWS * FEAT + b] = (float)(n > 0 ? n : 1);      // len output
    }
  }
}

// K4: one wave per output row j: gather weighted segment [t_lo..t_hi] of x;
// rows >= keep are zeros (d_out is poisoned).
__global__ __launch_bounds__(256) void emit_kernel(
    const float* __restrict__ x, const float* __restrict__ ws,
    float* __restrict__ out) {
  int gtid = blockIdx.x * 256 + threadIdx.x;
  int row  = gtid >> 6;          // b*TLEN + j
  int lane = gtid & 63;
  int b = row >> 12;
  int j = row & (TLEN - 1);
  int n = ((const int*)ws)[OFF_NF + b];
  int keep = n > 0 ? n : 1;
  float4 acc = make_float4(0.f, 0.f, 0.f, 0.f);
  if (j < keep) {
    const int* fpos = (const int*)ws + OFF_FPOS + b * TLEN;
    int t_lo = j ? fpos[j - 1] : 0;
    int t_hi = (j < n) ? fpos[j] : TLEN - 1;          // n==0: whole-seq hacc_f
    const float* w1 = ws + OFF_W1 + b * TLEN;
    const float* w2 = ws + OFF_W2 + b * TLEN;
    for (int t = t_lo; t <= t_hi; ++t) {
      float w = (j && t == t_lo) ? w2[t] : w1[t];
      float4 xv = *(const float4*)(x + ((size_t)b * TLEN + t) * FEAT + lane * 4);
      acc.x = fmaf(w, xv.x, acc.x);
      acc.y = fmaf(w, xv.y, acc.y);
      acc.z = fmaf(w, xv.z, acc.z);
      acc.w = fmaf(w, xv.w, acc.w);
    }
  }
  *(float4*)(out + (size_t)row * FEAT + lane * 4) = acc;
}

extern "C" void kernel_launch(void* const* d_in, const int* in_sizes, int n_in,
                              void* d_out, int out_size, void* d_ws, size_t ws_size,
                              hipStream_t stream) {
  const float* x      = (const float*)d_in[0];
  const float* conv_w = (const float*)d_in[1];
  const float* conv_b = (const float*)d_in[2];
  const float* lin_w  = (const float*)d_in[3];
  const float* lin_b  = (const float*)d_in[4];
  float* out = (float*)d_out;
  float* ws  = (float*)d_ws;

  hipLaunchKernelGGL(weff1_kernel, dim3(41), dim3(256), 0, stream,
                     conv_w, conv_b, lin_w, lin_b, ws);
  hipLaunchKernelGGL(pdalpha_kernel, dim3(NROWS / 128), dim3(256), 0, stream, x, ws);
  hipLaunchKernelGGL(scan_kernel, dim3(NB), dim3(1024), 0, stream, ws, out);
  hipLaunchKernelGGL(emit_kernel, dim3(NROWS / 4), dim3(256), 0, stream, x, ws, out);
}